// Round 8
// baseline (626.334 us; speedup 1.0000x reference)
//
#include <hip/hip_runtime.h>
#include <hip/hip_bf16.h>
#include <math.h>

#define N 4096
#define D 128
#define EPSV 1e-8f

typedef __attribute__((ext_vector_type(8))) short bf16x8;
typedef __attribute__((ext_vector_type(4))) float f32x4;

__device__ __forceinline__ float lrelu(float x){ return x > 0.f ? x : 0.2f*x; }

__device__ __forceinline__ ushort bf16_hi(float x){
  __hip_bfloat16 h = __float2bfloat16(x);
  return *reinterpret_cast<ushort*>(&h);
}
__device__ __forceinline__ float bf16_tof(ushort u){
  __hip_bfloat16 h = *reinterpret_cast<__hip_bfloat16*>(&u);
  return __bfloat162float(h);
}

__device__ __forceinline__ float wave_sum(float v){
  #pragma unroll
  for (int off = 32; off; off >>= 1) v += __shfl_down(v, off);
  return v;
}
__device__ __forceinline__ float block_sum256(float v, float* red){
  v = wave_sum(v);
  if ((threadIdx.x & 63) == 0) red[threadIdx.x >> 6] = v;
  __syncthreads();
  float r = (red[0] + red[1]) + (red[2] + red[3]);
  __syncthreads();
  return r;
}

// dis[i] = 1/sqrt(sum_j adj[i][j] + 1e-8)
__global__ void k_rowsum(const float* __restrict__ adj, float* __restrict__ dis){
  int i = blockIdx.x;
  const float4* row = reinterpret_cast<const float4*>(adj + (size_t)i * N);
  float s = 0.f;
  #pragma unroll
  for (int l = 0; l < 4; ++l){
    float4 v = row[threadIdx.x + l * 256];
    s += (v.x + v.y) + (v.z + v.w);
  }
  __shared__ float red[4];
  s = block_sum256(s, red);
  if (threadIdx.x == 0) dis[i] = 1.0f / sqrtf(s + EPSV);
}

// u = h @ W (split to bf16 hi/lo); p = h @ a_src ; q = h @ a_dst
__global__ void k_uhat2(const float* __restrict__ h, const float* __restrict__ W,
                        const float* __restrict__ aa,
                        ushort* __restrict__ u_hi, ushort* __restrict__ u_lo,
                        float* __restrict__ p, float* __restrict__ q){
  int i = blockIdx.x, t = threadIdx.x;
  __shared__ float hs[D];
  __shared__ float red[4];
  float hv = h[(size_t)i * D + t];
  hs[t] = hv;
  __syncthreads();
  float acc = 0.f;
  #pragma unroll 8
  for (int k = 0; k < D; ++k) acc = fmaf(hs[k], W[k * D + t], acc);
  ushort hh = bf16_hi(acc);
  u_hi[(size_t)i * D + t] = hh;
  u_lo[(size_t)i * D + t] = bf16_hi(acc - bf16_tof(hh));
  float pv = hv * aa[t];
  float qv = hv * aa[D + t];
  pv = wave_sum(pv); qv = wave_sum(qv);
  if ((t & 63) == 0){ red[t >> 6] = pv; red[2 + (t >> 6)] = qv; }
  __syncthreads();
  if (t == 0){ p[i] = red[0] + red[1]; q[i] = red[2] + red[3]; }
}

// transpose u_hi/u_lo (4096x128) -> packed uT_pk[n][kb][0:8]=hi, [8:16]=lo
__global__ void k_transposeU2(const ushort* __restrict__ u_hi, const ushort* __restrict__ u_lo,
                              ushort* __restrict__ uT_pk){
  __shared__ ushort T[64][136];
  const int tid = threadIdx.x;
  const int j0 = blockIdx.x * 64;
  for (int pass = 0; pass < 2; ++pass){
    const ushort* s = pass ? u_lo : u_hi;
    __syncthreads();
    #pragma unroll
    for (int l = 0; l < 4; ++l){
      int r = l * 16 + (tid >> 4);
      int c = (tid & 15) * 8;
      *reinterpret_cast<uint4*>(&T[r][c]) =
          *reinterpret_cast<const uint4*>(s + (size_t)(j0 + r) * D + c);
    }
    __syncthreads();
    const int dd = tid >> 1, half = tid & 1;
    #pragma unroll
    for (int g = 0; g < 4; ++g){
      int jb = half * 32 + g * 8;
      uint w0 = (uint)T[jb+0][dd] | ((uint)T[jb+1][dd] << 16);
      uint w1 = (uint)T[jb+2][dd] | ((uint)T[jb+3][dd] << 16);
      uint w2 = (uint)T[jb+4][dd] | ((uint)T[jb+5][dd] << 16);
      uint w3 = (uint)T[jb+6][dd] | ((uint)T[jb+7][dd] << 16);
      uint4 w; w.x = w0; w.y = w1; w.z = w2; w.w = w3;
      size_t off = ((size_t)dd * (N/8) + ((j0 + jb) >> 3)) * 16 + pass * 8;
      *reinterpret_cast<uint4*>(uT_pk + off) = w;
    }
  }
}

// ---------------------------------------------------------------------------
// Fused no-b MFMA gemm.  s_part[y][i][n] = sum_{j in slab y} exp(logit_ij)*u[j][n],
// l_part[y][i] = sum_j exp(logit_ij).   No max subtraction (range-safe, R5-R7).
// MODE 0: logit = dis_i dis_j adj_ij                      (iteration 0)
// MODE 1: logit = dis_i dis_j adj_ij + vsum_i . u_j       (iterations 1,2; b fused out)
// MODE 2: logit = lrelu(p_i + q_j)                        (attention term)
// Block 256 thr / 4 waves; tile M=64 x N=128; BK=32; grid (64, KS).
// Each wave owns 16 rows. corr tile computed per-wave via MFMA into Cs.
// ---------------------------------------------------------------------------
template<int MODE>
__global__ __launch_bounds__(256)
void k_gemm6(const float* __restrict__ adj, const float* __restrict__ dis,
             const float* __restrict__ p, const float* __restrict__ q,
             const ushort* __restrict__ uT_pk,
             const ushort* __restrict__ u_hi, const ushort* __restrict__ u_lo,
             const ushort* __restrict__ vs_hi, const ushort* __restrict__ vs_lo,
             float* __restrict__ s_part, float* __restrict__ l_part, int kRange)
{
  __shared__ float  As[64][36];    // fp32 adj tile (144B rows, 2-way banks)
  __shared__ ushort Bs[128][72];   // uT packed per out-dim: [hi 32 | lo 32 | pad]
  __shared__ float  Cs[4][16][36]; // per-wave corr tile [i_local][j_local]

  const int tid  = threadIdx.x;
  const int lane = tid & 63;
  const int wave = tid >> 6;
  const int row0 = blockIdx.x * 64;
  const int cl   = lane & 15;
  const int kgrp = (lane >> 4) * 8;
  const int k0b  = blockIdx.y * kRange;
  const int arow_w = row0 + wave * 16;       // wave's 16-row base

  const float dif = (MODE < 2) ? dis[arow_w + cl] : 0.f;
  const float pr  = (MODE == 2) ? p[arow_w + cl] : 0.f;

  f32x4 acc[8] = {};
  float lsum = 0.f;

  for (int kt = 0; kt < kRange; kt += 32){
    const int kb = k0b + kt;
    // -------- register-stage (dense, coalesced) --------
    float4 a_st[2];
    if (MODE != 2){
      #pragma unroll
      for (int i = 0; i < 2; ++i){
        int idx = i * 256 + tid;
        int r = idx >> 3, c = idx & 7;
        a_st[i] = *reinterpret_cast<const float4*>(adj + (size_t)(row0 + r) * N + kb + c * 4);
      }
    }
    uint4 b_st[4];
    const int kb8 = kb >> 3;
    #pragma unroll
    for (int i = 0; i < 4; ++i){
      int idx = i * 256 + tid;
      int n = idx >> 3, u = idx & 7;
      b_st[i] = *reinterpret_cast<const uint4*>(
          uT_pk + (size_t)n * (N/8) * 16 + (size_t)(kb8 + (u & 3)) * 16 + (u >> 2) * 8);
    }
    __syncthreads();
    if (MODE != 2){
      #pragma unroll
      for (int i = 0; i < 2; ++i){
        int idx = i * 256 + tid;
        int r = idx >> 3, c = idx & 7;
        *reinterpret_cast<float4*>(&As[r][c * 4]) = a_st[i];
      }
    }
    #pragma unroll
    for (int i = 0; i < 4; ++i){
      int idx = i * 256 + tid;
      int n = idx >> 3, u = idx & 7;
      *reinterpret_cast<uint4*>(&Bs[n][(u >> 2) * 32 + (u & 3) * 8]) = b_st[i];
    }
    __syncthreads();

    // -------- corr tile via MFMA (MODE 1): corr = vsum_tile @ Uslab^T --------
    if (MODE == 1){
      f32x4 cacc[2] = {};
      #pragma unroll
      for (int kk2 = 0; kk2 < D; kk2 += 32){
        const size_t voff = (size_t)(arow_w + cl) * D + kk2 + kgrp;
        bf16x8 vh = *reinterpret_cast<const bf16x8*>(vs_hi + voff);
        bf16x8 vl = *reinterpret_cast<const bf16x8*>(vs_lo + voff);
        #pragma unroll
        for (int nt = 0; nt < 2; ++nt){
          const size_t uoff = (size_t)(kb + nt * 16 + cl) * D + kk2 + kgrp;
          bf16x8 uh = *reinterpret_cast<const bf16x8*>(u_hi + uoff);
          bf16x8 ul = *reinterpret_cast<const bf16x8*>(u_lo + uoff);
          cacc[nt] = __builtin_amdgcn_mfma_f32_16x16x32_bf16(vh, uh, cacc[nt], 0, 0, 0);
          cacc[nt] = __builtin_amdgcn_mfma_f32_16x16x32_bf16(vh, ul, cacc[nt], 0, 0, 0);
          cacc[nt] = __builtin_amdgcn_mfma_f32_16x16x32_bf16(vl, uh, cacc[nt], 0, 0, 0);
        }
      }
      // D layout: j_local = nt*16 + (lane&15), i_local = (lane>>4)*4 + reg
      #pragma unroll
      for (int nt = 0; nt < 2; ++nt)
        #pragma unroll
        for (int r = 0; r < 4; ++r)
          Cs[wave][(lane >> 4) * 4 + r][nt * 16 + cl] = cacc[nt][r];
      __syncthreads();
    }

    // -------- per-k-slab aux vector --------
    float aux[8];
    if (MODE < 2){
      *reinterpret_cast<float4*>(aux)     = *reinterpret_cast<const float4*>(dis + kb + kgrp);
      *reinterpret_cast<float4*>(aux + 4) = *reinterpret_cast<const float4*>(dis + kb + kgrp + 4);
    } else {
      *reinterpret_cast<float4*>(aux)     = *reinterpret_cast<const float4*>(q + kb + kgrp);
      *reinterpret_cast<float4*>(aux + 4) = *reinterpret_cast<const float4*>(q + kb + kgrp + 4);
    }

    // -------- A fragment: logit -> exp -> split --------
    float ex[8];
    if (MODE == 2){
      #pragma unroll
      for (int e = 0; e < 8; ++e) ex[e] = __expf(lrelu(pr + aux[e]));
    } else {
      float av[8];
      const int rl = wave * 16 + cl;
      *reinterpret_cast<float4*>(av)     = *reinterpret_cast<const float4*>(&As[rl][kgrp]);
      *reinterpret_cast<float4*>(av + 4) = *reinterpret_cast<const float4*>(&As[rl][kgrp + 4]);
      if (MODE == 1){
        float cv[8];
        *reinterpret_cast<float4*>(cv)     = *reinterpret_cast<const float4*>(&Cs[wave][cl][kgrp]);
        *reinterpret_cast<float4*>(cv + 4) = *reinterpret_cast<const float4*>(&Cs[wave][cl][kgrp + 4]);
        #pragma unroll
        for (int e = 0; e < 8; ++e) ex[e] = __expf(av[e] * dif * aux[e] + cv[e]);
      } else {
        #pragma unroll
        for (int e = 0; e < 8; ++e) ex[e] = __expf(av[e] * dif * aux[e]);
      }
    }
    bf16x8 ahi, alo;
    #pragma unroll
    for (int e = 0; e < 8; ++e){
      lsum += ex[e];
      ushort hh = bf16_hi(ex[e]);
      ahi[e] = (short)hh;
      alo[e] = (short)bf16_hi(ex[e] - bf16_tof(hh));
    }

    // -------- main MFMA --------
    #pragma unroll
    for (int ct = 0; ct < 8; ++ct){
      const int col = ct * 16 + cl;
      bf16x8 bh = *reinterpret_cast<const bf16x8*>(&Bs[col][kgrp]);
      bf16x8 bl = *reinterpret_cast<const bf16x8*>(&Bs[col][32 + kgrp]);
      acc[ct] = __builtin_amdgcn_mfma_f32_16x16x32_bf16(ahi, bh, acc[ct], 0, 0, 0);
      acc[ct] = __builtin_amdgcn_mfma_f32_16x16x32_bf16(ahi, bl, acc[ct], 0, 0, 0);
      acc[ct] = __builtin_amdgcn_mfma_f32_16x16x32_bf16(alo, bh, acc[ct], 0, 0, 0);
    }
  }

  // row-sums of exp: lanes {cl, cl+16, cl+32, cl+48} hold partials of one row
  {
    float l = lsum;
    l += __shfl_xor(l, 16);
    l += __shfl_xor(l, 32);
    if (lane < 16)
      l_part[(size_t)blockIdx.y * N + arow_w + lane] = l;
  }
  // C/D layout: col = lane&15, row = (lane>>4)*4 + reg (verified R4-R7)
  {
    const int orow = arow_w + (lane >> 4) * 4;
    float* sp = s_part + ((size_t)blockIdx.y * N + orow) * D + cl;
    #pragma unroll
    for (int ct = 0; ct < 8; ++ct)
      #pragma unroll
      for (int r = 0; r < 4; ++r)
        sp[(size_t)r * D + ct * 16] = acc[ct][r];
  }
}

// reduce attn slabs -> s_attn (raw numerator) + l_a (denominator)
__global__ void k_reduce_attn(const float* __restrict__ s_part, const float* __restrict__ l_part,
                              float* __restrict__ s_attn, float* __restrict__ l_a, int ks){
  int row = blockIdx.x, t = threadIdx.x;
  float a = 0.f;
  for (int y = 0; y < ks; ++y) a += s_part[((size_t)y * N + row) * D + t];
  s_attn[(size_t)row * D + t] = a;
  if (t == 0){
    float la = 0.f;
    for (int y = 0; y < ks; ++y) la += l_part[(size_t)y * N + row];
    l_a[row] = la;
  }
}

// reduce slabs, normalize, squash; maintain vsum (fp32) and its bf16 split.
// STEP 0: vsum = v1. STEP 1: vsum += v2. STEP 2: blend attn, write out.
template<int STEP>
__global__ void k_reduce4(const float* __restrict__ s_part, const float* __restrict__ l_part,
                          const float* __restrict__ s_attn, const float* __restrict__ l_a,
                          float* __restrict__ vsum,
                          ushort* __restrict__ vh, ushort* __restrict__ vl,
                          float* __restrict__ out, int ks){
  int row = blockIdx.x, t = threadIdx.x;
  float a = 0.f;
  for (int y = 0; y < ks; ++y) a += s_part[((size_t)y * N + row) * D + t];
  __shared__ float lbs;
  __shared__ float red[2];
  if (t == 0){
    float lb = 0.f;
    for (int y = 0; y < ks; ++y) lb += l_part[(size_t)y * N + row];
    lbs = lb;
  }
  __syncthreads();
  float val = a / lbs;
  if (STEP == 2)
    val = 0.6f * val + 0.4f * s_attn[(size_t)row * D + t] / l_a[row];
  float ss = wave_sum(val * val);
  if ((t & 63) == 0) red[t >> 6] = ss;
  __syncthreads();
  float tot = red[0] + red[1];
  float n = sqrtf(tot);
  float f = n / ((1.0f + n) * (n + EPSV));
  float o = val * f;
  if (STEP == 2){
    out[(size_t)row * D + t] = o;
  } else {
    float nv = (STEP == 0) ? o : vsum[(size_t)row * D + t] + o;
    vsum[(size_t)row * D + t] = nv;
    ushort hh = bf16_hi(nv);
    vh[(size_t)row * D + t] = hh;
    vl[(size_t)row * D + t] = bf16_hi(nv - bf16_tof(hh));
  }
}

extern "C" void kernel_launch(void* const* d_in, const int* in_sizes, int n_in,
                              void* d_out, int out_size, void* d_ws, size_t ws_size,
                              hipStream_t stream) {
  const float* h   = (const float*)d_in[0];
  const float* adj = (const float*)d_in[1];
  const float* W   = (const float*)d_in[2];
  const float* aa  = (const float*)d_in[3];
  float* out = (float*)d_out;
  float* ws  = (float*)d_ws;

  float* dis    = ws;                     // 4096
  float* p      = ws + 4096;
  float* q      = ws + 8192;
  float* l_a    = ws + 12288;
  float* vsum   = ws + 16384;             // N*D = 524288
  float* l_part = vsum + (size_t)N * D;   // 16*4096 = 65536
  ushort* u_hi  = (ushort*)(l_part + 65536);
  ushort* u_lo  = u_hi  + (size_t)N * D;
  ushort* uT_pk = u_lo  + (size_t)N * D;              // (N/8)*D*16 ushorts
  ushort* vs_hi = uT_pk + (size_t)(N/8) * D * 16;
  ushort* vs_lo = vs_hi + (size_t)N * D;
  float* s_attn = (float*)(vs_lo + (size_t)N * D);    // 524288
  float* s_part = s_attn + (size_t)N * D;             // KS * 524288

  size_t base_floats = (size_t)(s_part - ws);
  int KS = 16;
  while (KS > 1 && (base_floats + (size_t)KS * N * D) * 4 > ws_size) KS >>= 1;
  int kRange = N / KS;
  dim3 gg(64, KS);

  k_rowsum<<<N, 256, 0, stream>>>(adj, dis);
  k_uhat2<<<N, 128, 0, stream>>>(h, W, aa, u_hi, u_lo, p, q);
  k_transposeU2<<<64, 256, 0, stream>>>(u_hi, u_lo, uT_pk);

  // attention term (iteration-invariant)
  k_gemm6<2><<<gg, 256, 0, stream>>>(adj, dis, p, q, uT_pk, u_hi, u_lo, vs_hi, vs_lo,
                                     s_part, l_part, kRange);
  k_reduce_attn<<<N, 128, 0, stream>>>(s_part, l_part, s_attn, l_a, KS);

  // it 0: v1 = squash(softmax(adj_norm) @ u); vsum = v1
  k_gemm6<0><<<gg, 256, 0, stream>>>(adj, dis, p, q, uT_pk, u_hi, u_lo, vs_hi, vs_lo,
                                     s_part, l_part, kRange);
  k_reduce4<0><<<N, 128, 0, stream>>>(s_part, l_part, s_attn, l_a, vsum, vs_hi, vs_lo, out, KS);

  // it 1: logits = adj_norm + v1@u^T (b fused out); vsum += v2
  k_gemm6<1><<<gg, 256, 0, stream>>>(adj, dis, p, q, uT_pk, u_hi, u_lo, vs_hi, vs_lo,
                                     s_part, l_part, kRange);
  k_reduce4<1><<<N, 128, 0, stream>>>(s_part, l_part, s_attn, l_a, vsum, vs_hi, vs_lo, out, KS);

  // it 2: logits = adj_norm + (v1+v2)@u^T; blend attention; squash -> out
  k_gemm6<1><<<gg, 256, 0, stream>>>(adj, dis, p, q, uT_pk, u_hi, u_lo, vs_hi, vs_lo,
                                     s_part, l_part, kRange);
  k_reduce4<2><<<N, 128, 0, stream>>>(s_part, l_part, s_attn, l_a, vsum, vs_hi, vs_lo, out, KS);
}